// Round 16
// baseline (215.219 us; speedup 1.0000x reference)
//
#include <hip/hip_runtime.h>
#include <stdint.h>

// KNN K=16 over x (B=2, N=8192, D=64) f32. Output int32 (2,B,N,K): nn_idx, center_idx.
// Pipeline: split_k (bf16 hi + residual norms + batch maxima via atomicMax) ->
// tau_p (MFMA hi-only min-ladders over 3072-sample, barrier-free streaming) ->
// tau_m (merge -> per-query threshold with PROVABLE Cauchy-Schwarz slop) ->
// filter_k (MFMA hi-only distance, barrier-free, accepts via LDS atomics) ->
// rerank_k (exact f64; ~49 survivors/query -> single bitonic round).
// Bound: |key_approx - key_true| <= 2(n_q E + e_q H) with e_i MEASURED in split_k,
// E = max e, H = Nmax + E. tau = u16_approx + 2*slop provably keeps all true
// top-16 (pigeonhole over the 3072-sample: sample-16th >= true d16).
constexpr int N_    = 8192;
constexpr int D_    = 64;
constexpr int K_    = 16;
constexpr int NQ    = 16384;          // 2*8192
constexpr int MS    = 8;              // m-superblocks per batch (1024 m each)
constexpr int CAPB  = 24;             // survivor cap per (query, superblock): E~6.1, +7.4 sigma
constexpr int NSL   = 6;              // tau sample slices (6 x 512 = 3072 samples)

typedef __attribute__((ext_vector_type(8))) short bf16x8;
typedef __attribute__((ext_vector_type(4))) float f32x4;

template<int JN>
__device__ __forceinline__ void topk_insertf(float (&key)[JN], float nk) {
    if (nk < key[JN - 1]) {
        bool c[JN];
#pragma unroll
        for (int j = 0; j < JN; ++j) c[j] = nk < key[j];
#pragma unroll
        for (int j = JN - 1; j >= 1; --j)
            key[j] = c[j - 1] ? key[j - 1] : (c[j] ? nk : key[j]);
        key[0] = c[0] ? nk : key[0];
    }
}

__device__ __forceinline__ unsigned short bf16_rne(float f) {
    uint32_t u = __float_as_uint(f);
    return (unsigned short)((u + 0x7FFFu + ((u >> 16) & 1u)) >> 16);   // no NaN in data
}

// K1: bf16 hi split + true squared norms + residual norms + per-batch maxima
// (uint-bits atomicMax: positive-float bit pattern is monotone; EHu memset to 0
// on stream before launch). 16 lanes/row; 16 rows/block (batch-aligned). grid=1024.
__global__ void __launch_bounds__(256) split_k(const float* __restrict__ x,
                                               unsigned short* __restrict__ xh,
                                               float* __restrict__ nrm,
                                               float* __restrict__ eres,
                                               unsigned int* __restrict__ EHu) {
    __shared__ float wmax[8];
    const int tid = (int)threadIdx.x;
    const int t = blockIdx.x * 256 + tid;                 // one float4 per thread
    const int row = t >> 4, seg = t & 15;
    const float4 v = reinterpret_cast<const float4*>(x)[t];
    float f[4] = {v.x, v.y, v.z, v.w};
    unsigned short h[4];
    float sq = 0.f, esq = 0.f;
#pragma unroll
    for (int j = 0; j < 4; ++j) {
        sq = fmaf(f[j], f[j], sq);
        h[j] = bf16_rne(f[j]);
        float hf = __uint_as_float((uint32_t)h[j] << 16);
        float r  = f[j] - hf;
        esq = fmaf(r, r, esq);
    }
    sq  += __shfl_xor(sq, 1, 16);  sq  += __shfl_xor(sq, 2, 16);
    sq  += __shfl_xor(sq, 4, 16);  sq  += __shfl_xor(sq, 8, 16);
    esq += __shfl_xor(esq, 1, 16); esq += __shfl_xor(esq, 2, 16);
    esq += __shfl_xor(esq, 4, 16); esq += __shfl_xor(esq, 8, 16);
    if (seg == 0) { nrm[row] = sq; eres[row] = sqrtf(esq); }
    ushort4 hv = {h[0], h[1], h[2], h[3]};
    reinterpret_cast<ushort4*>(xh)[t] = hv;

    // block maxima of {nrm, esq} -> 2 atomicMax per block (all rows same batch)
    float bn = (seg == 0) ? sq : 0.f, be = (seg == 0) ? esq : 0.f;
#pragma unroll
    for (int s = 1; s < 64; s <<= 1) {
        bn = fmaxf(bn, __shfl_xor(bn, s, 64));
        be = fmaxf(be, __shfl_xor(be, s, 64));
    }
    const int w = tid >> 6;
    if ((tid & 63) == 0) { wmax[w * 2] = bn; wmax[w * 2 + 1] = be; }
    __syncthreads();
    if (tid == 0) {
#pragma unroll
        for (int i = 1; i < 4; ++i) {
            bn = fmaxf(bn, wmax[i * 2]); be = fmaxf(be, wmax[i * 2 + 1]);
        }
        const int b = (int)(blockIdx.x * 16) >> 13;       // 16 rows per block
        atomicMax(&EHu[b * 2],     __float_as_uint(bn));  // max nrm (squared)
        atomicMax(&EHu[b * 2 + 1], __float_as_uint(be));  // max esq (squared)
    }
}

// K2a: MFMA tau partials, barrier-free streaming. Block = 128q x 512 samples
// (slice sh of the 3072-sample prefix); A/B frags gathered from L2-resident xh.
// Depth-1 min ladder per (lane,q) -> 192 partials/query (valid subset bound).
// grid = 128 q-tiles x 6 slices = 768 blocks of 256.
__global__ void __launch_bounds__(256, 4) tau_p(const unsigned short* __restrict__ xh,
                                                const float* __restrict__ nrm,
                                                float* __restrict__ part) {
    __shared__ alignas(16) float nrmS[512];                 // 2 KB sample norms
    const int tid = (int)threadIdx.x;
    const int bid = (int)blockIdx.x;
    const int qt  = bid / NSL, sh = bid % NSL;
    const int q0g = qt * 128;
    const int b   = q0g >> 13;                              // uniform (128 | 8192)
    const int q0l = q0g & (N_ - 1);
    const int s0  = sh * 512;
    const unsigned short* __restrict__ xhb = xh + (size_t)b * N_ * D_;
    const float* __restrict__ nb = nrm + b * N_;
    const int w = tid >> 6, lane = tid & 63;
    const int wq = w >> 1, wm = w & 1;                      // 64q x 32s wave subtile
    const int l15 = lane & 15, quad = lane >> 4;

    if (tid < 128) *(float4*)(nrmS + tid * 4) = *(const float4*)(nb + s0 + tid * 4);

    bf16x8 Af[2][4];                                        // A frags from global
#pragma unroll
    for (int half = 0; half < 2; ++half) {
        const int eo = (half * 4 + quad) * 8;               // element offset in row
#pragma unroll
        for (int tm = 0; tm < 4; ++tm)
            Af[half][tm] = *(const bf16x8*)(xhb + (size_t)(q0l + wq * 64 + tm * 16 + l15) * D_ + eo);
    }
    float lad[16];
#pragma unroll
    for (int j = 0; j < 16; ++j) lad[j] = __builtin_inff();
    __syncthreads();                                        // nrmS visible

    for (int mc = 0; mc < 8; ++mc) {
        const unsigned short* Bbase = xhb + (size_t)(s0 + mc * 64) * D_;
        bf16x8 Bf[2][2];                                    // coalesced line gathers
#pragma unroll
        for (int half = 0; half < 2; ++half) {
            const int eo = (half * 4 + quad) * 8;
#pragma unroll
            for (int tn = 0; tn < 2; ++tn)
                Bf[half][tn] = *(const bf16x8*)(Bbase + (size_t)(wm * 32 + tn * 16 + l15) * D_ + eo);
        }
        f32x4 acc[4][2] = {};
#pragma unroll
        for (int half = 0; half < 2; ++half)
#pragma unroll
            for (int tm = 0; tm < 4; ++tm)
#pragma unroll
                for (int tn = 0; tn < 2; ++tn)
                    acc[tm][tn] = __builtin_amdgcn_mfma_f32_16x16x32_bf16(Af[half][tm], Bf[half][tn], acc[tm][tn], 0, 0, 0);
        // epilogue: C/D col=lane&15 (sample), row=quad*4+reg (q); depth-1 min
#pragma unroll
        for (int tn = 0; tn < 2; ++tn) {
            const float nm = nrmS[mc * 64 + wm * 32 + tn * 16 + l15];
#pragma unroll
            for (int tm = 0; tm < 4; ++tm)
#pragma unroll
                for (int reg = 0; reg < 4; ++reg)
                    lad[tm * 4 + reg] = fminf(lad[tm * 4 + reg],
                                              fmaf(-2.f, acc[tm][tn][reg], nm));
        }
    }
    // part[q][192]: offset = sh*32 + wm*16 + l15
#pragma unroll
    for (int tm = 0; tm < 4; ++tm)
#pragma unroll
        for (int reg = 0; reg < 4; ++reg) {
            const int q = q0g + wq * 64 + tm * 16 + quad * 4 + reg;
            part[(size_t)q * 192 + sh * 32 + wm * 16 + l15] = lad[tm * 4 + reg];
        }
}

// K2b: merge 192 partials/query -> tau with provable slop. grid = NQ/64 = 256.
__global__ void __launch_bounds__(64) tau_m(const float* __restrict__ part,
                                            const float* __restrict__ nrm,
                                            const float* __restrict__ eres,
                                            const unsigned int* __restrict__ EHu,
                                            float* __restrict__ tau) {
    const int q = blockIdx.x * 64 + (int)threadIdx.x;
    const int b = q >> 13;
    const float4* p = reinterpret_cast<const float4*>(part + (size_t)q * 192);
    float key[K_];
#pragma unroll
    for (int j = 0; j < K_; ++j) key[j] = __builtin_inff();
    for (int i = 0; i < 48; ++i) {
        float4 v = p[i];
        topk_insertf<K_>(key, v.x); topk_insertf<K_>(key, v.y);
        topk_insertf<K_>(key, v.z); topk_insertf<K_>(key, v.w);
    }
    const float Nmax = sqrtf(__uint_as_float(EHu[b * 2]))     * 1.0002f + 1e-6f;
    const float Emax = sqrtf(__uint_as_float(EHu[b * 2 + 1])) * 1.0002f + 1e-7f;
    const float H = Nmax + Emax;                            // >= max ||xh_m||
    const float nq = sqrtf(nrm[q]) * 1.0001f, eq = eres[q];
    tau[q] = key[15] + 4.f * (nq * Emax + eq * H) + 6e-3f;  // 2*s_q + f32 fudge
}

// K3: MFMA filter, barrier-free streaming. Block = 128q x 1024m, 16 chunks of
// 64m. A/B fragments gathered straight from L2-resident xh (wave's B load =
// 16 rows x one 64-B line -> ideal line count). No LDS staging, no per-chunk
// barriers; 4 blocks/CU overlap the latency. Accepts -> LDS per-query lists
// (DS atomics). grid = 2*64*8 = 1024 blocks of 256.
__global__ void __launch_bounds__(256, 4) filter_k(const unsigned short* __restrict__ xh,
                                                   const float* __restrict__ nrm,
                                                   const float* __restrict__ tau,
                                                   unsigned short* __restrict__ cnt_pb,
                                                   unsigned short* __restrict__ buf2) {
    __shared__ alignas(16) float nrmS[1024];                // 4 KB superblock norms
    __shared__ unsigned short lists[128 * CAPB];            // 6 KB
    __shared__ unsigned int cntL[128];
    const int tid = (int)threadIdx.x;
    const int bid = (int)blockIdx.x;
    const int b  = bid >> 9;
    const int qt = (bid >> 3) & 63;
    const int ms = bid & 7;
    const int q0 = qt * 128;
    const unsigned short* __restrict__ xhb = xh + (size_t)b * N_ * D_;
    const float* __restrict__ nb = nrm + b * N_;
    const int w = tid >> 6, lane = tid & 63;
    const int wq = w >> 1, wm = w & 1;                      // 64q x 32m wave subtile
    const int l15 = lane & 15, quad = lane >> 4;

    *(float4*)(nrmS + tid * 4) = *(const float4*)(nb + ms * 1024 + tid * 4);
    if (tid < 128) cntL[tid] = 0;

    bf16x8 Af[2][4];                                        // A frags from global
#pragma unroll
    for (int half = 0; half < 2; ++half) {
        const int eo = (half * 4 + quad) * 8;
#pragma unroll
        for (int tm = 0; tm < 4; ++tm)
            Af[half][tm] = *(const bf16x8*)(xhb + (size_t)(q0 + wq * 64 + tm * 16 + l15) * D_ + eo);
    }
    f32x4 t4v[4];
#pragma unroll
    for (int tm = 0; tm < 4; ++tm)
        t4v[tm] = *(const f32x4*)(tau + (b << 13) + q0 + wq * 64 + tm * 16 + quad * 4);
    __syncthreads();                                        // nrmS visible

    for (int mc = 0; mc < 16; ++mc) {
        const unsigned short* Bbase = xhb + (size_t)(ms * 1024 + mc * 64) * D_;
        bf16x8 Bf[2][2];                                    // coalesced line gathers
#pragma unroll
        for (int half = 0; half < 2; ++half) {
            const int eo = (half * 4 + quad) * 8;
#pragma unroll
            for (int tn = 0; tn < 2; ++tn)
                Bf[half][tn] = *(const bf16x8*)(Bbase + (size_t)(wm * 32 + tn * 16 + l15) * D_ + eo);
        }
        f32x4 acc[4][2] = {};
#pragma unroll
        for (int half = 0; half < 2; ++half)
#pragma unroll
            for (int tm = 0; tm < 4; ++tm)
#pragma unroll
                for (int tn = 0; tn < 2; ++tn)
                    acc[tm][tn] = __builtin_amdgcn_mfma_f32_16x16x32_bf16(Af[half][tm], Bf[half][tn], acc[tm][tn], 0, 0, 0);
        // epilogue: C/D col=lane&15 (m), row=quad*4+reg (q); accept key <= tau
#pragma unroll
        for (int tn = 0; tn < 2; ++tn) {
            const int mloc = mc * 64 + wm * 32 + tn * 16 + l15;
            const float nm = nrmS[mloc];
            const unsigned short mid = (unsigned short)(ms * 1024 + mloc);
#pragma unroll
            for (int tm = 0; tm < 4; ++tm)
#pragma unroll
                for (int reg = 0; reg < 4; ++reg) {
                    float keyf = fmaf(-2.f, acc[tm][tn][reg], nm);
                    if (keyf <= t4v[tm][reg]) {             // rare (~0.6%)
                        int ql = wq * 64 + tm * 16 + quad * 4 + reg;
                        unsigned pos = atomicAdd(&cntL[ql], 1u);    // LDS atomic
                        if (pos < CAPB) lists[ql * CAPB + pos] = mid;
                    }
                }
        }
    }
    __syncthreads();                                        // all waves' accepts visible
    if (tid < 128) {                                        // flush to fixed slots
        const int q = (b << 13) + q0 + tid;
        unsigned cn = cntL[tid]; cn = cn < CAPB ? cn : CAPB;
        cnt_pb[(size_t)q * MS + ms] = (unsigned short)cn;
        unsigned short* dst = buf2 + ((size_t)q * MS + ms) * CAPB;
        for (unsigned i = 0; i < cn; ++i) dst[i] = lists[tid * CAPB + i];
    }
}

// K4: exact f64 rerank, wave-per-query. ~49 survivors/query -> single round for
// ~99.7% of queries (loop handles the rest). Each lane computes one candidate's
// full 64-dim f64 distance; selection via 64-lane bitonic sort of packed u64
// (dist,id) keys. block 256 = 4 waves = 4 queries; grid = NQ/4 = 4096.
__global__ void __launch_bounds__(256) rerank_k(const float* __restrict__ x,
                                                const unsigned short* __restrict__ cnt_pb,
                                                const unsigned short* __restrict__ buf2,
                                                int* __restrict__ out) {
    __shared__ float Qs[4 * 64];                           // 1 KB query rows
    __shared__ unsigned short ids[4 * MS * CAPB];          // 1.5 KB compacted survivors
    const int tid = (int)threadIdx.x;
    const int w = tid >> 6, lane = tid & 63;
    const int q = blockIdx.x * 4 + w;
    const int b = q >> 13, n = q & (N_ - 1);
    const float* __restrict__ xb = x + (size_t)b * N_ * D_;
    Qs[w * 64 + lane] = xb[(size_t)n * D_ + lane];

    int off[MS + 1]; off[0] = 0;                           // all lanes compute same
#pragma unroll
    for (int ms = 0; ms < MS; ++ms) {
        int c = (int)cnt_pb[(size_t)q * MS + ms]; c = c < CAPB ? c : CAPB;
        off[ms + 1] = off[ms] + c;
    }
    const int total = off[MS];                             // >= 16 guaranteed (true top-16 pass)
    for (int idx = lane; idx < total; idx += 64) {         // compact ids into LDS
        int ms = 0;
#pragma unroll
        for (int t = 1; t < MS; ++t) ms += (idx >= off[t]) ? 1 : 0;
        ids[(w * MS) * CAPB + idx] = buf2[((size_t)q * MS + ms) * CAPB + (idx - off[ms])];
    }
    __syncthreads();

    unsigned long long v = ~0ull;
    int consumed = 0;
    bool first = true;
    while (first || consumed < total) {
        const int myIdx = first ? lane : consumed + lane - 16;
        const bool take = (first || lane >= 16) && myIdx < total;
        unsigned long long nk = ~0ull;
        if (take) {
            const int id = (int)ids[(w * MS) * CAPB + myIdx];
            const float* __restrict__ crow = xb + (size_t)id * D_;
            double a0 = 0.0, a1 = 0.0, a2 = 0.0, a3 = 0.0;
#pragma unroll
            for (int j = 0; j < 16; ++j) {
                const float4 c  = *(const float4*)(crow + j * 4);        // per-lane gather
                const float4 qv = *(const float4*)(Qs + w * 64 + j * 4); // uniform -> broadcast
                double d0 = (double)qv.x - (double)c.x; a0 = fma(d0, d0, a0);
                double d1 = (double)qv.y - (double)c.y; a1 = fma(d1, d1, a1);
                double d2 = (double)qv.z - (double)c.z; a2 = fma(d2, d2, a2);
                double d3 = (double)qv.w - (double)c.w; a3 = fma(d3, d3, a3);
            }
            double s = (a0 + a1) + (a2 + a3);
            // s >= 0 -> f64 bits order-preserving; low 13 mantissa bits carry the id
            // for exact (dist, id) lexicographic compare (ties -> lower id).
            nk = ((unsigned long long)__double_as_longlong(s) & ~0x1FFFull) | (unsigned)id;
        }
        if (first || lane >= 16) v = nk;                   // lanes 0-15 keep running top-16
        // 64-lane bitonic sort ascending (21 steps)
#pragma unroll
        for (int k = 2; k <= 64; k <<= 1)
#pragma unroll
            for (int j = k >> 1; j > 0; j >>= 1) {
                unsigned long long o = __shfl_xor(v, j, 64);
                const bool keepmin = (((lane & k) == 0) == ((lane & j) == 0));
                unsigned long long mn = v < o ? v : o;
                unsigned long long mx = v < o ? o : v;
                v = keepmin ? mn : mx;
            }
        consumed += first ? 64 : 48;
        first = false;
    }
    if (lane < K_) {
        out[(size_t)q * K_ + lane]                   = (int)(v & 0x1FFFull);  // nn_idx
        out[(size_t)NQ * K_ + (size_t)q * K_ + lane] = n;                     // center_idx
    }
}

extern "C" void kernel_launch(void* const* d_in, const int* in_sizes, int n_in,
                              void* d_out, int out_size, void* d_ws, size_t ws_size,
                              hipStream_t stream) {
    const float* x = (const float*)d_in[0];
    int* out = (int*)d_out;
    char* ws = (char*)d_ws;
    float*          nrm    = (float*)ws;                          //  64 KB @ 0
    float*          tau    = (float*)(ws + (64 << 10));           //  64 KB
    float*          eres   = (float*)(ws + (128 << 10));          //  64 KB
    unsigned int*   EHu    = (unsigned int*)(ws + (192 << 10));   //  16 B
    unsigned short* cnt_pb = (unsigned short*)(ws + (256 << 10)); // 256 KB
    unsigned short* xh     = (unsigned short*)(ws + (1 << 20));   //   2 MB
    unsigned short* buf2   = (unsigned short*)(ws + (5 << 20));   // 6.3 MB (16384*8*24*2)
    float*          part   = (float*)(ws + (5 << 20));            // 12.6 MB, ALIASES buf2:
    // part is written by tau_p and fully consumed by tau_m BEFORE filter_k writes buf2.

    hipMemsetAsync(EHu, 0, 16, stream);                     // init for atomicMax
    hipLaunchKernelGGL(split_k,  dim3(1024),      dim3(256), 0, stream, x, xh, nrm, eres, EHu);
    hipLaunchKernelGGL(tau_p,    dim3(128 * NSL), dim3(256), 0, stream, xh, nrm, part);
    hipLaunchKernelGGL(tau_m,    dim3(256),       dim3(64),  0, stream, part, nrm, eres, EHu, tau);
    hipLaunchKernelGGL(filter_k, dim3(1024),      dim3(256), 0, stream, xh, nrm, tau, cnt_pb, buf2);
    hipLaunchKernelGGL(rerank_k, dim3(4096),      dim3(256), 0, stream, x, cnt_pb, buf2, out);
}